// Round 9
// baseline (380.563 us; speedup 1.0000x reference)
//
#include <hip/hip_runtime.h>

typedef __bf16 bf16x8 __attribute__((ext_vector_type(8)));
typedef float f32x4 __attribute__((ext_vector_type(4)));

// workspace layout (bf16 elements):
//   [0)      Weff   [112][128]  (unit, k)  pre-scaled by 2*log2e, col100 = 2*log2e*b_enc
//   [14336)  whh_p  [3][112][128]          r,z pre-scaled by log2e (col100 = log2e*(b_ih+b_hh));
//                                          n pre-scaled by 2*log2e (col100 = 2*log2e*b_hh_n)
//   [57344)  w1_p   [64][128]  (yunit, k)  col100 = b1
#define WS_WENC 0
#define WS_WHH  14336
#define WS_W1   57344
#define LOG2E 1.4426950408889634f

__device__ __forceinline__ float fast_exp2(float x) {
#if __has_builtin(__builtin_amdgcn_exp2f)
  return __builtin_amdgcn_exp2f(x);
#else
  return exp2f(x);
#endif
}
__device__ __forceinline__ float fast_rcp(float x) {
#if __has_builtin(__builtin_amdgcn_rcpf)
  return __builtin_amdgcn_rcpf(x);
#else
  return 1.f / x;
#endif
}

__global__ void prep_kernel(const float* __restrict__ w_enc,
                            const float* __restrict__ b_enc,
                            const float* __restrict__ w_hh,
                            const float* __restrict__ b_ih,
                            const float* __restrict__ b_hh,
                            const float* __restrict__ w1,
                            const float* __restrict__ b1,
                            __bf16* __restrict__ ws) {
  int idx = blockIdx.x * 256 + threadIdx.x;
  if (idx < 14336) {
    // Weff[i][n] = w_enc[i][n] + sum_k w_enc[i][100+k]*cos(2pi k n/100) - w_enc[i][151+k]*sin(2pi k n/100)
    int i = idx >> 7, n = idx & 127;
    float acc = 0.f;
    if (i < 100) {
      if (n < 100) {
        const float* wr = w_enc + i * 202;
        acc = wr[n];
        #pragma unroll 1
        for (int k = 0; k <= 50; ++k) {
          int m = (k * n) % 100;                 // exact range reduction
          float th = 0.062831853071795864f * (float)m;
          float s, c;
          __sincosf(th, &s, &c);
          acc += wr[100 + k] * c - wr[151 + k] * s;
        }
        acc *= 2.f * LOG2E;
      } else if (n == 100) {
        acc = 2.f * LOG2E * b_enc[i];
      }
    }
    ws[idx] = (__bf16)acc;
  } else if (idx < 57344) {
    int j = idx - 14336;
    int g = j / 14336;
    int rem = j - g * 14336;
    int u2 = rem >> 7, c2 = rem & 127;
    float scale = (g == 2) ? 2.f * LOG2E : LOG2E;
    float v = 0.f;
    if (u2 < 100) {
      if (c2 < 100) v = scale * w_hh[(g * 100 + u2) * 100 + c2];
      else if (c2 == 100) {
        v = (g == 2) ? scale * b_hh[200 + u2]
                     : scale * (b_ih[g * 100 + u2] + b_hh[g * 100 + u2]);
      }
    }
    ws[idx] = (__bf16)v;
  } else if (idx < 65536) {
    int j = idx - 57344;
    int r2 = j >> 7, c2 = j & 127;
    float v = 0.f;
    if (r2 < 50) {
      if (c2 < 100) v = w1[r2 * 100 + c2];
      else if (c2 == 100) v = b1[r2];
    }
    ws[idx] = (__bf16)v;
  }
}

__device__ __forceinline__ f32x4 mfma16(bf16x8 a, bf16x8 b, f32x4 c) {
  return __builtin_amdgcn_mfma_f32_16x16x32_bf16(a, b, c, 0, 0, 0);
}
// input already scaled by log2e:  sigm = rcp(1 + 2^-a)
__device__ __forceinline__ float sigm2(float a) { return fast_rcp(1.f + fast_exp2(-a)); }
// input already scaled by 2*log2e: tanh = 2*rcp(1 + 2^-b) - 1
__device__ __forceinline__ float tanh2(float b) { return fmaf(2.f, fast_rcp(1.f + fast_exp2(-b)), -1.f); }

// block = 448 threads = 7 waves, 64 sequences per block (FOUR 16-seq MFMA groups
// sharing the per-wave resident w_hh fragments).
// wave w owns hidden units [16w, 16w+16) for ALL groups.
// y-matmul transposed (w1 tile as A from LDS wYl, h as B): 16 (group,tile) tasks
// strided over the 7 waves (wave w: tasks w, w+7, w+14).
// Post-B1 rotating pipeline (R8's proven 2-live-acc pattern, extended):
//   g1-MFMA, g0-elem, g2-MFMA, g1-elem, g3-MFMA, g2-elem, g3-elem
// so gate-MFMA latency hides under the previous group's elementwise, and at most
// ~2 accumulator sets are live (no spill).
// Rationale (R9): VALU+MFMA issue was ~82%; remaining idle is per-barrier fixed
// cost. 64 seqs/block halves barriers per sequence-step without adding work
// (R4's mistake) or live state (R5's mistake).
// Output staged in LDS, flushed coalesced after the loop: no in-loop global stores.
// MFMA 16x16x32_bf16; C/D layout: col = lane&15, row = 4*(lane>>4)+reg (HW-verified).
// Bias trick: h column 100 pinned to 1.0; weight column 100 carries the biases.
// All LDS tiles stride 136 elements (272 B) -> 2-way bank aliasing only (free).
// LDS ~65 KB -> 2 blocks/CU; grid 512 -> all blocks resident from cycle 0.
__global__ __launch_bounds__(448, 4)
void gru_main(const float* __restrict__ enc,
              const float* __restrict__ w_ih,
              const float* __restrict__ b_ih,
              const float* __restrict__ w2,
              const float* __restrict__ b2,
              const __bf16* __restrict__ ws,
              float* __restrict__ out) {
  __shared__ __align__(16) __bf16 hbuf[2][64 * 136];  // [buf][seq 0..63][unit]
  __shared__ __align__(16) __bf16 wYl[64 * 136];      // w1_p restrided 128->136
  __shared__ __align__(16) float xq[4][16][4];        // y tile-partials [group][seq][tile]
  __shared__ __align__(16) float outstage[64 * 52];   // [seq][t], stride 52
  __shared__ float w2l[64];

  const int tid = threadIdx.x;
  const int w = tid >> 6;
  const int l = tid & 63;
  const int c = l & 15;        // tile column / seq-in-group
  const int grp = l >> 4;      // 0..3
  const int klo = 8 * grp;     // within-K-tile offset
  const int seqbase = blockIdx.x * 64;
  const int u = 16 * w + c;    // this lane's hidden unit
  const bool vu = (u < 100);
  const float padf = (u == 100) ? 1.f : 0.f;  // constant-1 bias column at unit 100

  // init LDS h-buffers: pad cols zero except col 100 = 1.0
  for (int i = tid; i < 2 * 64 * 136; i += 448)
    hbuf[0][i] = (__bf16)((i % 136 == 100) ? 1.f : 0.f);
  // stage w1_p into LDS with stride restrip 128 -> 136 (1024 16B chunks)
  for (int i = tid; i < 1024; i += 448) {
    int row = i >> 4, off = (i & 15) * 8;
    *(bf16x8*)&wYl[row * 136 + off] = *(const bf16x8*)(ws + WS_W1 + row * 128 + off);
  }
  if (tid < 64) w2l[tid] = (tid < 50) ? w2[tid] : 0.f;

  // per-lane constants (pre-scaled)
  float wihr = 0.f, wihz = 0.f, wihn = 0.f, bin_ = 0.f;
  if (vu) {
    wihr = w_ih[u] * LOG2E;
    wihz = w_ih[100 + u] * LOG2E;
    wihn = w_ih[200 + u] * (2.f * LOG2E);
    bin_ = b_ih[200 + u] * (2.f * LOG2E);
  }
  const float b2v = b2[0];

  // resident w_hh fragments (shared across all four seq groups)
  bf16x8 wR[3][4];
  #pragma unroll
  for (int g = 0; g < 3; ++g) {
    #pragma unroll
    for (int kt = 0; kt < 4; ++kt)
      wR[g][kt] = *(const bf16x8*)(ws + WS_WHH + (g * 112 + u) * 128 + kt * 32 + klo);
  }

  // ---------- encoder: h0 = tanh(sig @ Weff^T), DFT + bias folded into Weff ----------
  float h_old[4][4];
  {
    #pragma unroll
    for (int g = 0; g < 4; ++g) {
      f32x4 hc = {0.f, 0.f, 0.f, 0.f};
      const float* srow = enc + (size_t)(seqbase + 16 * g + c) * 100;
      #pragma unroll
      for (int kt = 0; kt < 4; ++kt) {
        bf16x8 wE = *(const bf16x8*)(ws + WS_WENC + u * 128 + kt * 32 + klo);
        int t0 = kt * 32 + klo;
        float f0 = 0.f, f1 = 0.f, f2 = 0.f, f3 = 0.f, f4 = 0.f, f5 = 0.f, f6 = 0.f, f7 = 0.f;
        if (t0 + 8 <= 100) {
          float4 va = *(const float4*)(srow + t0);
          float4 vb = *(const float4*)(srow + t0 + 4);
          f0 = va.x; f1 = va.y; f2 = va.z; f3 = va.w;
          f4 = vb.x; f5 = vb.y; f6 = vb.z; f7 = vb.w;
        } else if (t0 < 100) {  // t0 == 96: 4 real + slot 100 = 1.0 (bias)
          float4 va = *(const float4*)(srow + t0);
          f0 = va.x; f1 = va.y; f2 = va.z; f3 = va.w;
          f4 = 1.f;
        }
        bf16x8 a;
        a[0] = (__bf16)f0; a[1] = (__bf16)f1; a[2] = (__bf16)f2; a[3] = (__bf16)f3;
        a[4] = (__bf16)f4; a[5] = (__bf16)f5; a[6] = (__bf16)f6; a[7] = (__bf16)f7;
        hc = mfma16(a, wE, hc);
      }
      #pragma unroll
      for (int r = 0; r < 4; ++r) h_old[g][r] = vu ? tanh2(hc[r]) : 0.f;
    }
  }

  __syncthreads();  // LDS init + wYl/w2l staging complete
  #pragma unroll
  for (int g = 0; g < 4; ++g)
    #pragma unroll
    for (int r = 0; r < 4; ++r)
      hbuf[0][(16 * g + 4 * grp + r) * 136 + u] = (__bf16)(vu ? h_old[g][r] : padf);
  __syncthreads();

  // helper: gate MFMAs for group g from hbuf[rb]
  auto gatesMFMA = [&](int rb, int g, f32x4& Cr, f32x4& Cz, f32x4& Cn) {
    Cr = f32x4{0.f, 0.f, 0.f, 0.f};
    Cz = f32x4{0.f, 0.f, 0.f, 0.f};
    Cn = f32x4{0.f, 0.f, 0.f, 0.f};
    #pragma unroll
    for (int kt = 0; kt < 4; ++kt) {
      bf16x8 a = *(const bf16x8*)&hbuf[rb][(16 * g + c) * 136 + kt * 32 + klo];
      Cr = mfma16(a, wR[0][kt], Cr);
      Cz = mfma16(a, wR[1][kt], Cz);
      Cn = mfma16(a, wR[2][kt], Cn);
    }
  };
  // helper: xv assembly + out staging + gate elementwise + h write for group g
  auto elemwise = [&](int t, int wb, int g, f32x4& Cr, f32x4& Cz, f32x4& Cn) {
    float xv[4];
    if (t > 0) {
      #pragma unroll
      for (int r = 0; r < 4; ++r) {
        float4 xp = *(const float4*)xq[g][4 * grp + r];
        xv[r] = b2v + xp.x + xp.y + xp.z + xp.w;
      }
      if (c == 0 && w == g) {
        #pragma unroll
        for (int r = 0; r < 4; ++r)
          outstage[(16 * g + 4 * grp + r) * 52 + (t - 1)] = xv[r];
      }
    } else {
      #pragma unroll
      for (int r = 0; r < 4; ++r)
        xv[r] = enc[(size_t)(seqbase + 16 * g + 4 * grp + r) * 100 + 99];
    }
    #pragma unroll
    for (int r = 0; r < 4; ++r) {
      float ar = fmaf(xv[r], wihr, Cr[r]);   // log2e-scaled, bias included
      float rg = sigm2(ar);
      float az = fmaf(xv[r], wihz, Cz[r]);
      float zg = sigm2(az);
      float bn = fmaf(rg, Cn[r], fmaf(xv[r], wihn, bin_));  // 2log2e-scaled
      float ng = tanh2(bn);
      float hn = fmaf(zg, h_old[g][r] - ng, ng);
      h_old[g][r] = hn;
      hbuf[wb][(16 * g + 4 * grp + r) * 136 + u] = (__bf16)(vu ? hn : padf);
    }
  };

  // ---------- decoder: t=0..50; interval t computes y_{t-1} (t>0) and h_{t+1} (t<50) ----------
  #pragma unroll 1
  for (int t = 0; t <= 50; ++t) {
    const int rb = t & 1;
    // ---- y-phase (transposed): 16 (group,tile) tasks strided over 7 waves ----
    if (t > 0) {
      #pragma unroll 1
      for (int tk = w; tk < 16; tk += 7) {
        const int g = tk >> 2;
        const int tile = tk & 3;
        f32x4 Cy = {0.f, 0.f, 0.f, 0.f};
        #pragma unroll
        for (int kt = 0; kt < 4; ++kt) {
          bf16x8 wyf = *(const bf16x8*)&wYl[(tile * 16 + c) * 136 + kt * 32 + klo];
          bf16x8 ag = *(const bf16x8*)&hbuf[rb][(16 * g + c) * 136 + kt * 32 + klo];
          Cy = mfma16(wyf, ag, Cy);
        }
        float p = 0.f;
        #pragma unroll
        for (int r = 0; r < 4; ++r) {
          float v = Cy[r];
          v = fmaxf(v, 0.01f * v);     // leaky_relu (b1 folded via bias column)
          p = fmaf(w2l[tile * 16 + 4 * grp + r], v, p);
        }
        p += __shfl_xor(p, 16);
        p += __shfl_xor(p, 32);
        if (l < 16) xq[g][l][tile] = p;
      }
    }
    // ---- group 0 gate MFMAs before B1 ----
    f32x4 CrA, CzA, CnA;
    if (t < 50) gatesMFMA(rb, 0, CrA, CzA, CnA);
    __syncthreads();  // barrier 1: xq ready

    if (t < 50) {
      const int wb = rb ^ 1;
      // rotating pipeline: next group's MFMAs issue before current group's elementwise
      f32x4 CrB, CzB, CnB;
      gatesMFMA(rb, 1, CrB, CzB, CnB);
      elemwise(t, wb, 0, CrA, CzA, CnA);
      gatesMFMA(rb, 2, CrA, CzA, CnA);
      elemwise(t, wb, 1, CrB, CzB, CnB);
      gatesMFMA(rb, 3, CrB, CzB, CnB);
      elemwise(t, wb, 2, CrA, CzA, CnA);
      elemwise(t, wb, 3, CrB, CzB, CnB);
    } else {
      // t == 50: stage the final y_49 for all four groups
      if (w < 4 && c == 0) {
        #pragma unroll
        for (int r = 0; r < 4; ++r) {
          float4 xp = *(const float4*)xq[w][4 * grp + r];
          outstage[(16 * w + 4 * grp + r) * 52 + 49] = b2v + xp.x + xp.y + xp.z + xp.w;
        }
      }
    }
    __syncthreads();  // barrier 2: h ready for next step
  }

  // ---------- coalesced output flush ----------
  for (int i = tid; i < 64 * 50; i += 448) {
    int s = i / 50, tp = i - s * 50;
    out[(size_t)(seqbase + s) * 50 + tp] = outstage[s * 52 + tp];
  }
}

extern "C" void kernel_launch(void* const* d_in, const int* in_sizes, int n_in,
                              void* d_out, int out_size, void* d_ws, size_t ws_size,
                              hipStream_t stream) {
  const float* enc   = (const float*)d_in[0];
  const float* w_enc = (const float*)d_in[1];
  const float* b_enc = (const float*)d_in[2];
  const float* w_ih  = (const float*)d_in[3];
  const float* b_ih  = (const float*)d_in[4];
  const float* w_hh  = (const float*)d_in[5];
  const float* b_hh  = (const float*)d_in[6];
  const float* w1    = (const float*)d_in[7];
  const float* b1    = (const float*)d_in[8];
  const float* w2    = (const float*)d_in[9];
  const float* b2    = (const float*)d_in[10];
  __bf16* ws = (__bf16*)d_ws;
  float* out = (float*)d_out;

  prep_kernel<<<256, 256, 0, stream>>>(w_enc, b_enc, w_hh, b_ih, b_hh, w1, b1, ws);
  gru_main<<<32768 / 64, 448, 0, stream>>>(enc, w_ih, b_ih, w2, b2, ws, out);
}

// Round 11
// 361.711 us; speedup vs baseline: 1.0521x; 1.0521x over previous
//
#include <hip/hip_runtime.h>

typedef __bf16 bf16x8 __attribute__((ext_vector_type(8)));
typedef float f32x4 __attribute__((ext_vector_type(4)));

// workspace layout (bf16 elements):
//   [0)      Weff   [112][128]  (unit, k)  pre-scaled by 2*log2e, col100 = 2*log2e*b_enc
//   [14336)  whh_p  [3][112][128]          r,z pre-scaled by log2e (col100 = log2e*(b_ih+b_hh));
//                                          n pre-scaled by 2*log2e (col100 = 2*log2e*b_hh_n)
//   [57344)  w1_p   [64][128]  (yunit, k)  col100 = b1
#define WS_WENC 0
#define WS_WHH  14336
#define WS_W1   57344
#define LOG2E 1.4426950408889634f

__device__ __forceinline__ float fast_exp2(float x) {
#if __has_builtin(__builtin_amdgcn_exp2f)
  return __builtin_amdgcn_exp2f(x);
#else
  return exp2f(x);
#endif
}
__device__ __forceinline__ float fast_rcp(float x) {
#if __has_builtin(__builtin_amdgcn_rcpf)
  return __builtin_amdgcn_rcpf(x);
#else
  return 1.f / x;
#endif
}

__global__ void prep_kernel(const float* __restrict__ w_enc,
                            const float* __restrict__ b_enc,
                            const float* __restrict__ w_hh,
                            const float* __restrict__ b_ih,
                            const float* __restrict__ b_hh,
                            const float* __restrict__ w1,
                            const float* __restrict__ b1,
                            __bf16* __restrict__ ws) {
  int idx = blockIdx.x * 256 + threadIdx.x;
  if (idx < 14336) {
    // Weff[i][n] = w_enc[i][n] + sum_k w_enc[i][100+k]*cos(2pi k n/100) - w_enc[i][151+k]*sin(2pi k n/100)
    int i = idx >> 7, n = idx & 127;
    float acc = 0.f;
    if (i < 100) {
      if (n < 100) {
        const float* wr = w_enc + i * 202;
        acc = wr[n];
        #pragma unroll 1
        for (int k = 0; k <= 50; ++k) {
          int m = (k * n) % 100;                 // exact range reduction
          float th = 0.062831853071795864f * (float)m;
          float s, c;
          __sincosf(th, &s, &c);
          acc += wr[100 + k] * c - wr[151 + k] * s;
        }
        acc *= 2.f * LOG2E;
      } else if (n == 100) {
        acc = 2.f * LOG2E * b_enc[i];
      }
    }
    ws[idx] = (__bf16)acc;
  } else if (idx < 57344) {
    int j = idx - 14336;
    int g = j / 14336;
    int rem = j - g * 14336;
    int u2 = rem >> 7, c2 = rem & 127;
    float scale = (g == 2) ? 2.f * LOG2E : LOG2E;
    float v = 0.f;
    if (u2 < 100) {
      if (c2 < 100) v = scale * w_hh[(g * 100 + u2) * 100 + c2];
      else if (c2 == 100) {
        v = (g == 2) ? scale * b_hh[200 + u2]
                     : scale * (b_ih[g * 100 + u2] + b_hh[g * 100 + u2]);
      }
    }
    ws[idx] = (__bf16)v;
  } else if (idx < 65536) {
    int j = idx - 57344;
    int r2 = j >> 7, c2 = j & 127;
    float v = 0.f;
    if (r2 < 50) {
      if (c2 < 100) v = w1[r2 * 100 + c2];
      else if (c2 == 100) v = b1[r2];
    }
    ws[idx] = (__bf16)v;
  }
}

__device__ __forceinline__ f32x4 mfma16(bf16x8 a, bf16x8 b, f32x4 c) {
  return __builtin_amdgcn_mfma_f32_16x16x32_bf16(a, b, c, 0, 0, 0);
}
// input already scaled by log2e:  sigm = rcp(1 + 2^-a)
__device__ __forceinline__ float sigm2(float a) { return fast_rcp(1.f + fast_exp2(-a)); }
// input already scaled by 2*log2e: tanh = 2*rcp(1 + 2^-b) - 1
__device__ __forceinline__ float tanh2(float b) { return fmaf(2.f, fast_rcp(1.f + fast_exp2(-b)), -1.f); }

// block = 896 threads = 14 waves = TWO independent 7-wave teams; 64 seqs/block.
// Team T (waves 7T..7T+6) runs the R8-proven program on groups 2T, 2T+1
// (seqs 32T..32T+31). Per-wave register/live state is byte-identical to R8
// (VGPR=64, no spill); only the block got wider, so each CU can carry up to
// 2 blocks x 14 waves = 28 waves of independent work to fill barrier-edge idle
// (R8: ~12 waves, VALUBusy 61%).
// Within a team: wave wt owns hidden units [16wt, 16wt+16) for both its groups;
// y-matmul transposed (w1 tile as A from shared LDS wYl, h as B):
//   wt 0-2 -> first group tiles 0-2; wt 3 -> tile 3 both; wt 4-6 -> second 0-2.
// Phase order per step (R8): y-MFMA+xq | g0-gate-MFMA | B1 | g1-gate-MFMA first,
// then g0-elem, g1-elem | B2. Output staged in LDS, coalesced flush at the end.
// MFMA 16x16x32_bf16; C/D layout: col = lane&15, row = 4*(lane>>4)+reg (HW-verified).
// Bias trick: h column 100 pinned to 1.0; weight column 100 carries the biases.
// All LDS tiles stride 136 elements (272 B) -> 2-way bank aliasing only (free).
__global__ __launch_bounds__(896, 2)
void gru_main(const float* __restrict__ enc,
              const float* __restrict__ w_ih,
              const float* __restrict__ b_ih,
              const float* __restrict__ w2,
              const float* __restrict__ b2,
              const __bf16* __restrict__ ws,
              float* __restrict__ out) {
  __shared__ __align__(16) __bf16 hbuf[2][64 * 136];  // [buf][seq 0..63][unit]
  __shared__ __align__(16) __bf16 wYl[64 * 136];      // w1_p restrided 128->136 (shared by teams)
  __shared__ __align__(16) float xq[4][16][4];        // y tile-partials [group][seq][tile]
  __shared__ __align__(16) float outstage[64 * 52];   // [seq][t], stride 52
  __shared__ float w2l[64];

  const int tid = threadIdx.x;
  const int w = tid >> 6;      // 0..13
  const int T = (w >= 7);      // team
  const int wt = w - 7 * T;    // wave-in-team 0..6
  const int l = tid & 63;
  const int c = l & 15;        // tile column / seq-in-group
  const int grp = l >> 4;      // 0..3
  const int klo = 8 * grp;     // within-K-tile offset
  const int seqbase = blockIdx.x * 64;
  const int u = 16 * wt + c;   // this lane's hidden unit
  const bool vu = (u < 100);
  const float padf = (u == 100) ? 1.f : 0.f;  // constant-1 bias column at unit 100
  const int g0 = 2 * T;        // team's first global group
  const int g1 = 2 * T + 1;    // team's second global group

  // init LDS h-buffers: pad cols zero except col 100 = 1.0
  for (int i = tid; i < 2 * 64 * 136; i += 896)
    hbuf[0][i] = (__bf16)((i % 136 == 100) ? 1.f : 0.f);
  // stage w1_p into LDS with stride restrip 128 -> 136 (1024 16B chunks)
  for (int i = tid; i < 1024; i += 896) {
    int row = i >> 4, off = (i & 15) * 8;
    *(bf16x8*)&wYl[row * 136 + off] = *(const bf16x8*)(ws + WS_W1 + row * 128 + off);
  }
  if (tid < 64) w2l[tid] = (tid < 50) ? w2[tid] : 0.f;

  // per-lane constants (pre-scaled)
  float wihr = 0.f, wihz = 0.f, wihn = 0.f, bin_ = 0.f;
  if (vu) {
    wihr = w_ih[u] * LOG2E;
    wihz = w_ih[100 + u] * LOG2E;
    wihn = w_ih[200 + u] * (2.f * LOG2E);
    bin_ = b_ih[200 + u] * (2.f * LOG2E);
  }
  // y-task assignment within team
  const int ytile = (wt < 3) ? wt : ((wt == 3) ? 3 : (wt - 4));
  const int yg = (wt < 4) ? g0 : g1;   // group for single-task waves
  const bool dual = (wt == 3);
  const float b2v = b2[0];

  // resident w_hh fragments (shared across the team's two seq groups)
  bf16x8 wR[3][4];
  #pragma unroll
  for (int g = 0; g < 3; ++g) {
    #pragma unroll
    for (int kt = 0; kt < 4; ++kt)
      wR[g][kt] = *(const bf16x8*)(ws + WS_WHH + (g * 112 + u) * 128 + kt * 32 + klo);
  }

  // ---------- encoder: h0 = tanh(sig @ Weff^T), DFT + bias folded into Weff ----------
  float h_old[2][4];
  {
    #pragma unroll
    for (int gl = 0; gl < 2; ++gl) {
      f32x4 hc = {0.f, 0.f, 0.f, 0.f};
      const float* srow = enc + (size_t)(seqbase + 16 * (g0 + gl) + c) * 100;
      #pragma unroll
      for (int kt = 0; kt < 4; ++kt) {
        bf16x8 wE = *(const bf16x8*)(ws + WS_WENC + u * 128 + kt * 32 + klo);
        int t0 = kt * 32 + klo;
        float f0 = 0.f, f1 = 0.f, f2 = 0.f, f3 = 0.f, f4 = 0.f, f5 = 0.f, f6 = 0.f, f7 = 0.f;
        if (t0 + 8 <= 100) {
          float4 va = *(const float4*)(srow + t0);
          float4 vb = *(const float4*)(srow + t0 + 4);
          f0 = va.x; f1 = va.y; f2 = va.z; f3 = va.w;
          f4 = vb.x; f5 = vb.y; f6 = vb.z; f7 = vb.w;
        } else if (t0 < 100) {  // t0 == 96: 4 real + slot 100 = 1.0 (bias)
          float4 va = *(const float4*)(srow + t0);
          f0 = va.x; f1 = va.y; f2 = va.z; f3 = va.w;
          f4 = 1.f;
        }
        bf16x8 a;
        a[0] = (__bf16)f0; a[1] = (__bf16)f1; a[2] = (__bf16)f2; a[3] = (__bf16)f3;
        a[4] = (__bf16)f4; a[5] = (__bf16)f5; a[6] = (__bf16)f6; a[7] = (__bf16)f7;
        hc = mfma16(a, wE, hc);
      }
      #pragma unroll
      for (int r = 0; r < 4; ++r) h_old[gl][r] = vu ? tanh2(hc[r]) : 0.f;
    }
  }

  __syncthreads();  // LDS init + wYl/w2l staging complete
  #pragma unroll
  for (int gl = 0; gl < 2; ++gl)
    #pragma unroll
    for (int r = 0; r < 4; ++r)
      hbuf[0][(16 * (g0 + gl) + 4 * grp + r) * 136 + u] = (__bf16)(vu ? h_old[gl][r] : padf);
  __syncthreads();

  // ---------- decoder: t=0..50; interval t computes y_{t-1} (t>0) and h_{t+1} (t<50) ----------
  #pragma unroll 1
  for (int t = 0; t <= 50; ++t) {
    const int rb = t & 1;
    // ---- y-phase (transposed): Cy rows = y-units, cols = seqs ----
    if (t > 0) {
      const int ntask = dual ? 2 : 1;
      #pragma unroll 1
      for (int gi = 0; gi < ntask; ++gi) {
        const int g = dual ? (g0 + gi) : yg;
        f32x4 Cy = {0.f, 0.f, 0.f, 0.f};
        #pragma unroll
        for (int kt = 0; kt < 4; ++kt) {
          bf16x8 wyf = *(const bf16x8*)&wYl[(ytile * 16 + c) * 136 + kt * 32 + klo];
          bf16x8 ag = *(const bf16x8*)&hbuf[rb][(16 * g + c) * 136 + kt * 32 + klo];
          Cy = mfma16(wyf, ag, Cy);
        }
        float p = 0.f;
        #pragma unroll
        for (int r = 0; r < 4; ++r) {
          float v = Cy[r];
          v = fmaxf(v, 0.01f * v);     // leaky_relu (b1 folded via bias column)
          p = fmaf(w2l[ytile * 16 + 4 * grp + r], v, p);
        }
        p += __shfl_xor(p, 16);
        p += __shfl_xor(p, 32);
        if (l < 16) xq[g][l][ytile] = p;
      }
    }
    // ---- first-group gate MFMAs before B1 (halve cross-barrier accs) ----
    f32x4 Cr0 = {0.f,0.f,0.f,0.f}, Cz0 = {0.f,0.f,0.f,0.f}, Cn0 = {0.f,0.f,0.f,0.f};
    if (t < 50) {
      #pragma unroll
      for (int kt = 0; kt < 4; ++kt) {
        bf16x8 a = *(const bf16x8*)&hbuf[rb][(16 * g0 + c) * 136 + kt * 32 + klo];
        Cr0 = mfma16(a, wR[0][kt], Cr0);
        Cz0 = mfma16(a, wR[1][kt], Cz0);
        Cn0 = mfma16(a, wR[2][kt], Cn0);
      }
    }
    __syncthreads();  // barrier 1: xq ready

    if (t < 50) {
      const int wb = rb ^ 1;
      // ---- second-group gate MFMAs issued FIRST (hbuf[rb] still valid; latency
      //      hides under first group's xv assembly + elementwise) ----
      f32x4 Cr1 = {0.f,0.f,0.f,0.f}, Cz1 = {0.f,0.f,0.f,0.f}, Cn1 = {0.f,0.f,0.f,0.f};
      #pragma unroll
      for (int kt = 0; kt < 4; ++kt) {
        bf16x8 a = *(const bf16x8*)&hbuf[rb][(16 * g1 + c) * 136 + kt * 32 + klo];
        Cr1 = mfma16(a, wR[0][kt], Cr1);
        Cz1 = mfma16(a, wR[1][kt], Cz1);
        Cn1 = mfma16(a, wR[2][kt], Cn1);
      }
      // ---- first group: xv + out staging + elementwise + h write ----
      {
        float xv[4];
        if (t > 0) {
          #pragma unroll
          for (int r = 0; r < 4; ++r) {
            float4 xp = *(const float4*)xq[g0][4 * grp + r];
            xv[r] = b2v + xp.x + xp.y + xp.z + xp.w;
          }
          if (c == 0 && wt == 0) {
            #pragma unroll
            for (int r = 0; r < 4; ++r)
              outstage[(16 * g0 + 4 * grp + r) * 52 + (t - 1)] = xv[r];
          }
        } else {
          #pragma unroll
          for (int r = 0; r < 4; ++r)
            xv[r] = enc[(size_t)(seqbase + 16 * g0 + 4 * grp + r) * 100 + 99];
        }
        #pragma unroll
        for (int r = 0; r < 4; ++r) {
          float ar = fmaf(xv[r], wihr, Cr0[r]);
          float rg = sigm2(ar);
          float az = fmaf(xv[r], wihz, Cz0[r]);
          float zg = sigm2(az);
          float bn = fmaf(rg, Cn0[r], fmaf(xv[r], wihn, bin_));
          float ng = tanh2(bn);
          float hn = fmaf(zg, h_old[0][r] - ng, ng);
          h_old[0][r] = hn;
          hbuf[wb][(16 * g0 + 4 * grp + r) * 136 + u] = (__bf16)(vu ? hn : padf);
        }
      }
      // ---- second group: xv + out staging + elementwise + h write ----
      {
        float xv[4];
        if (t > 0) {
          #pragma unroll
          for (int r = 0; r < 4; ++r) {
            float4 xp = *(const float4*)xq[g1][4 * grp + r];
            xv[r] = b2v + xp.x + xp.y + xp.z + xp.w;
          }
          if (c == 0 && wt == 3) {
            #pragma unroll
            for (int r = 0; r < 4; ++r)
              outstage[(16 * g1 + 4 * grp + r) * 52 + (t - 1)] = xv[r];
          }
        } else {
          #pragma unroll
          for (int r = 0; r < 4; ++r)
            xv[r] = enc[(size_t)(seqbase + 16 * g1 + 4 * grp + r) * 100 + 99];
        }
        #pragma unroll
        for (int r = 0; r < 4; ++r) {
          float ar = fmaf(xv[r], wihr, Cr1[r]);
          float rg = sigm2(ar);
          float az = fmaf(xv[r], wihz, Cz1[r]);
          float zg = sigm2(az);
          float bn = fmaf(rg, Cn1[r], fmaf(xv[r], wihn, bin_));
          float ng = tanh2(bn);
          float hn = fmaf(zg, h_old[1][r] - ng, ng);
          h_old[1][r] = hn;
          hbuf[wb][(16 * g1 + 4 * grp + r) * 136 + u] = (__bf16)(vu ? hn : padf);
        }
      }
    } else {
      // t == 50: only the final out staging (y_49) — within team, wt 0 / 3
      #pragma unroll
      for (int gl = 0; gl < 2; ++gl) {
        const int g = g0 + gl;
        if (c == 0 && wt == 3 * gl) {
          #pragma unroll
          for (int r = 0; r < 4; ++r) {
            float4 xp = *(const float4*)xq[g][4 * grp + r];
            outstage[(16 * g + 4 * grp + r) * 52 + (t - 1)] =
                b2v + xp.x + xp.y + xp.z + xp.w;
          }
        }
      }
    }
    __syncthreads();  // barrier 2: h ready for next step
  }

  // ---------- coalesced output flush ----------
  for (int i = tid; i < 64 * 50; i += 896) {
    int s = i / 50, tp = i - s * 50;
    out[(size_t)(seqbase + s) * 50 + tp] = outstage[s * 52 + tp];
  }
}

extern "C" void kernel_launch(void* const* d_in, const int* in_sizes, int n_in,
                              void* d_out, int out_size, void* d_ws, size_t ws_size,
                              hipStream_t stream) {
  const float* enc   = (const float*)d_in[0];
  const float* w_enc = (const float*)d_in[1];
  const float* b_enc = (const float*)d_in[2];
  const float* w_ih  = (const float*)d_in[3];
  const float* b_ih  = (const float*)d_in[4];
  const float* w_hh  = (const float*)d_in[5];
  const float* b_hh  = (const float*)d_in[6];
  const float* w1    = (const float*)d_in[7];
  const float* b1    = (const float*)d_in[8];
  const float* w2    = (const float*)d_in[9];
  const float* b2    = (const float*)d_in[10];
  __bf16* ws = (__bf16*)d_ws;
  float* out = (float*)d_out;

  prep_kernel<<<256, 256, 0, stream>>>(w_enc, b_enc, w_hh, b_ih, b_hh, w1, b1, ws);
  gru_main<<<32768 / 64, 896, 0, stream>>>(enc, w_ih, b_ih, w2, b2, ws, out);
}

// Round 12
// 312.633 us; speedup vs baseline: 1.2173x; 1.1570x over previous
//
#include <hip/hip_runtime.h>

typedef __bf16 bf16x8 __attribute__((ext_vector_type(8)));
typedef float f32x4 __attribute__((ext_vector_type(4)));

// workspace layout (bf16 elements):
//   [0)      Weff   [112][128]  (unit, k)  pre-scaled by 2*log2e, col100 = 2*log2e*b_enc
//   [14336)  whh_p  [3][112][128]          r,z pre-scaled by log2e (col100 = log2e*(b_ih+b_hh));
//                                          n pre-scaled by 2*log2e (col100 = 2*log2e*b_hh_n)
//   [57344)  w1_p   [64][128]  (yunit, k)  col100 = b1
#define WS_WENC 0
#define WS_WHH  14336
#define WS_W1   57344
#define LOG2E 1.4426950408889634f
// hbuf row stride 104 (13x8: rows 16B-aligned; lane-bank step 20 mod 32 -> 2-way, free).
// Per-buffer length 3360 = 32*104 + 32 guard: the K=128 MFMA overrun (row*104+127 max)
// stays INSIDE the buffer -> reads finite bf16 (R10's NaN came from overrunning into
// float-typed LDS). Weight K-cols 101..127 are true zeros, so overrun contributes x*0.
#define HSTR 104
#define HBUFLEN 3360

__device__ __forceinline__ float fast_exp2(float x) {
#if __has_builtin(__builtin_amdgcn_exp2f)
  return __builtin_amdgcn_exp2f(x);
#else
  return exp2f(x);
#endif
}
__device__ __forceinline__ float fast_rcp(float x) {
#if __has_builtin(__builtin_amdgcn_rcpf)
  return __builtin_amdgcn_rcpf(x);
#else
  return 1.f / x;
#endif
}

__global__ void prep_kernel(const float* __restrict__ w_enc,
                            const float* __restrict__ b_enc,
                            const float* __restrict__ w_hh,
                            const float* __restrict__ b_ih,
                            const float* __restrict__ b_hh,
                            const float* __restrict__ w1,
                            const float* __restrict__ b1,
                            __bf16* __restrict__ ws) {
  int idx = blockIdx.x * 256 + threadIdx.x;
  if (idx < 14336) {
    // Weff[i][n] = w_enc[i][n] + sum_k w_enc[i][100+k]*cos(2pi k n/100) - w_enc[i][151+k]*sin(2pi k n/100)
    int i = idx >> 7, n = idx & 127;
    float acc = 0.f;
    if (i < 100) {
      if (n < 100) {
        const float* wr = w_enc + i * 202;
        acc = wr[n];
        #pragma unroll 1
        for (int k = 0; k <= 50; ++k) {
          int m = (k * n) % 100;                 // exact range reduction
          float th = 0.062831853071795864f * (float)m;
          float s, c;
          __sincosf(th, &s, &c);
          acc += wr[100 + k] * c - wr[151 + k] * s;
        }
        acc *= 2.f * LOG2E;
      } else if (n == 100) {
        acc = 2.f * LOG2E * b_enc[i];
      }
    }
    ws[idx] = (__bf16)acc;
  } else if (idx < 57344) {
    int j = idx - 14336;
    int g = j / 14336;
    int rem = j - g * 14336;
    int u2 = rem >> 7, c2 = rem & 127;
    float scale = (g == 2) ? 2.f * LOG2E : LOG2E;
    float v = 0.f;
    if (u2 < 100) {
      if (c2 < 100) v = scale * w_hh[(g * 100 + u2) * 100 + c2];
      else if (c2 == 100) {
        v = (g == 2) ? scale * b_hh[200 + u2]
                     : scale * (b_ih[g * 100 + u2] + b_hh[g * 100 + u2]);
      }
    }
    ws[idx] = (__bf16)v;
  } else if (idx < 65536) {
    int j = idx - 57344;
    int r2 = j >> 7, c2 = j & 127;
    float v = 0.f;
    if (r2 < 50) {
      if (c2 < 100) v = w1[r2 * 100 + c2];
      else if (c2 == 100) v = b1[r2];
    }
    ws[idx] = (__bf16)v;
  }
}

__device__ __forceinline__ f32x4 mfma16(bf16x8 a, bf16x8 b, f32x4 c) {
  return __builtin_amdgcn_mfma_f32_16x16x32_bf16(a, b, c, 0, 0, 0);
}
// input already scaled by log2e:  sigm = rcp(1 + 2^-a)
__device__ __forceinline__ float sigm2(float a) { return fast_rcp(1.f + fast_exp2(-a)); }
// input already scaled by 2*log2e: tanh = 2*rcp(1 + 2^-b) - 1
__device__ __forceinline__ float tanh2(float b) { return fmaf(2.f, fast_rcp(1.f + fast_exp2(-b)), -1.f); }

// R8 structure (best: 319us, 7-wave barrier, VALUBusy 61%) with the LDS shrink done
// SAFELY: hbuf stride 136 -> 104 (+32-elem guard per buffer, see HSTR note above),
// total LDS 42.5 -> ~37.4 KB so FOUR blocks/CU fit -> the whole 1024-block grid is
// resident (R8: 3 blocks/CU -> 256-block tail round at 1/3 throughput).
// All h-writes guarded u < HSTR (lanes u=104..111 are dead pad).
// Micro-fold: b2v absorbed into the tile-3 xq partial (wave 3 adds it once per seq).
// Everything else identical to R8: 7 waves, 32 seqs (2 groups), wY in LDS (136),
// g0-MFMA pre-B1 / g1-MFMA post-B1 rotation, outstage + coalesced flush.
// MFMA 16x16x32_bf16; C/D layout: col = lane&15, row = 4*(lane>>4)+reg (HW-verified).
// Bias trick: h column 100 pinned to 1.0; weight column 100 carries the biases.
__global__ __launch_bounds__(448, 4)
void gru_main(const float* __restrict__ enc,
              const float* __restrict__ w_ih,
              const float* __restrict__ b_ih,
              const float* __restrict__ w2,
              const float* __restrict__ b2,
              const __bf16* __restrict__ ws,
              float* __restrict__ out) {
  __shared__ __align__(16) __bf16 hbuf[2][HBUFLEN];   // [buf][seq*HSTR + unit], +guard
  __shared__ __align__(16) __bf16 wYl[64 * 136];      // w1_p restrided 128->136
  __shared__ __align__(16) float xq[2][16][4];        // y tile-partials [group][seq][tile]
  __shared__ __align__(16) float outstage[32 * 52];   // [seq][t], stride 52
  __shared__ float w2l[64];

  const int tid = threadIdx.x;
  const int w = tid >> 6;
  const int l = tid & 63;
  const int c = l & 15;        // tile column / seq-in-group
  const int grp = l >> 4;      // 0..3
  const int klo = 8 * grp;     // within-K-tile offset
  const int seqbase = blockIdx.x * 32;
  const int u = 16 * w + c;    // this lane's hidden unit
  const bool vu = (u < 100);
  const float padf = (u == 100) ? 1.f : 0.f;  // constant-1 bias column at unit 100

  // init LDS h-buffers (incl. guards): pad cols zero except col 100 = 1.0
  for (int i = tid; i < 2 * HBUFLEN; i += 448)
    hbuf[0][i] = (__bf16)((i % HSTR == 100) ? 1.f : 0.f);
  // stage w1_p into LDS with stride restrip 128 -> 136 (1024 16B chunks)
  for (int i = tid; i < 1024; i += 448) {
    int row = i >> 4, off = (i & 15) * 8;
    *(bf16x8*)&wYl[row * 136 + off] = *(const bf16x8*)(ws + WS_W1 + row * 128 + off);
  }
  if (tid < 64) w2l[tid] = (tid < 50) ? w2[tid] : 0.f;

  // per-lane constants (pre-scaled)
  float wihr = 0.f, wihz = 0.f, wihn = 0.f, bin_ = 0.f;
  if (vu) {
    wihr = w_ih[u] * LOG2E;
    wihz = w_ih[100 + u] * LOG2E;
    wihn = w_ih[200 + u] * (2.f * LOG2E);
    bin_ = b_ih[200 + u] * (2.f * LOG2E);
  }
  // y-task assignment
  const int ytile = (w < 3) ? w : ((w == 3) ? 3 : (w - 4));
  const int yg0 = (w < 4) ? 0 : 1;
  const bool dual = (w == 3);
  const float b2v = b2[0];

  // resident w_hh fragments (shared across both seq groups)
  bf16x8 wR[3][4];
  #pragma unroll
  for (int g = 0; g < 3; ++g) {
    #pragma unroll
    for (int kt = 0; kt < 4; ++kt)
      wR[g][kt] = *(const bf16x8*)(ws + WS_WHH + (g * 112 + u) * 128 + kt * 32 + klo);
  }

  // ---------- encoder: h0 = tanh(sig @ Weff^T), DFT + bias folded into Weff ----------
  float h_old[2][4];
  {
    #pragma unroll
    for (int g = 0; g < 2; ++g) {
      f32x4 hc = {0.f, 0.f, 0.f, 0.f};
      const float* srow = enc + (size_t)(seqbase + 16 * g + c) * 100;
      #pragma unroll
      for (int kt = 0; kt < 4; ++kt) {
        bf16x8 wE = *(const bf16x8*)(ws + WS_WENC + u * 128 + kt * 32 + klo);
        int t0 = kt * 32 + klo;
        float f0 = 0.f, f1 = 0.f, f2 = 0.f, f3 = 0.f, f4 = 0.f, f5 = 0.f, f6 = 0.f, f7 = 0.f;
        if (t0 + 8 <= 100) {
          float4 va = *(const float4*)(srow + t0);
          float4 vb = *(const float4*)(srow + t0 + 4);
          f0 = va.x; f1 = va.y; f2 = va.z; f3 = va.w;
          f4 = vb.x; f5 = vb.y; f6 = vb.z; f7 = vb.w;
        } else if (t0 < 100) {  // t0 == 96: 4 real + slot 100 = 1.0 (bias)
          float4 va = *(const float4*)(srow + t0);
          f0 = va.x; f1 = va.y; f2 = va.z; f3 = va.w;
          f4 = 1.f;
        }
        bf16x8 a;
        a[0] = (__bf16)f0; a[1] = (__bf16)f1; a[2] = (__bf16)f2; a[3] = (__bf16)f3;
        a[4] = (__bf16)f4; a[5] = (__bf16)f5; a[6] = (__bf16)f6; a[7] = (__bf16)f7;
        hc = mfma16(a, wE, hc);
      }
      #pragma unroll
      for (int r = 0; r < 4; ++r) h_old[g][r] = vu ? tanh2(hc[r]) : 0.f;
    }
  }

  __syncthreads();  // LDS init + wYl/w2l staging complete
  if (u < HSTR) {
    #pragma unroll
    for (int g = 0; g < 2; ++g)
      #pragma unroll
      for (int r = 0; r < 4; ++r)
        hbuf[0][(16 * g + 4 * grp + r) * HSTR + u] = (__bf16)(vu ? h_old[g][r] : padf);
  }
  __syncthreads();

  // ---------- decoder: t=0..50; interval t computes y_{t-1} (t>0) and h_{t+1} (t<50) ----------
  #pragma unroll 1
  for (int t = 0; t <= 50; ++t) {
    const int rb = t & 1;
    // ---- y-phase (transposed): Cy rows = y-units, cols = seqs ----
    if (t > 0) {
      if (!dual) {
        const int g = yg0;
        f32x4 Cy = {0.f, 0.f, 0.f, 0.f};
        #pragma unroll
        for (int kt = 0; kt < 4; ++kt) {
          bf16x8 wyf = *(const bf16x8*)&wYl[(ytile * 16 + c) * 136 + kt * 32 + klo];
          bf16x8 ag = *(const bf16x8*)&hbuf[rb][(16 * g + c) * HSTR + kt * 32 + klo];
          Cy = mfma16(wyf, ag, Cy);
        }
        float p = 0.f;
        #pragma unroll
        for (int r = 0; r < 4; ++r) {
          float v = Cy[r];
          v = fmaxf(v, 0.01f * v);     // leaky_relu (b1 folded via bias column)
          p = fmaf(w2l[ytile * 16 + 4 * grp + r], v, p);
        }
        p += __shfl_xor(p, 16);
        p += __shfl_xor(p, 32);
        if (l < 16) xq[g][l][ytile] = p;
      } else {
        // wave 3: tile 3 for both groups; b2v folded into this partial
        #pragma unroll 1
        for (int g = 0; g < 2; ++g) {
          f32x4 Cy = {0.f, 0.f, 0.f, 0.f};
          #pragma unroll
          for (int kt = 0; kt < 4; ++kt) {
            bf16x8 wyf = *(const bf16x8*)&wYl[(48 + c) * 136 + kt * 32 + klo];
            bf16x8 ag = *(const bf16x8*)&hbuf[rb][(16 * g + c) * HSTR + kt * 32 + klo];
            Cy = mfma16(wyf, ag, Cy);
          }
          float p = 0.f;
          #pragma unroll
          for (int r = 0; r < 4; ++r) {
            float v = Cy[r];
            v = fmaxf(v, 0.01f * v);
            p = fmaf(w2l[48 + 4 * grp + r], v, p);
          }
          p += __shfl_xor(p, 16);
          p += __shfl_xor(p, 32);
          if (l < 16) xq[g][l][3] = p + b2v;
        }
      }
    }
    // ---- gate MFMAs for GROUP 0 only before B1 (halve cross-barrier accs) ----
    f32x4 Cr0 = {0.f,0.f,0.f,0.f}, Cz0 = {0.f,0.f,0.f,0.f}, Cn0 = {0.f,0.f,0.f,0.f};
    if (t < 50) {
      #pragma unroll
      for (int kt = 0; kt < 4; ++kt) {
        bf16x8 a = *(const bf16x8*)&hbuf[rb][c * HSTR + kt * 32 + klo];
        Cr0 = mfma16(a, wR[0][kt], Cr0);
        Cz0 = mfma16(a, wR[1][kt], Cz0);
        Cn0 = mfma16(a, wR[2][kt], Cn0);
      }
    }
    __syncthreads();  // barrier 1: xq ready

    if (t < 50) {
      const int wb = rb ^ 1;
      // ---- group 1 gate MFMAs issued FIRST (hbuf[rb] still valid; latency hides
      //      under g0's xv assembly + elementwise) ----
      f32x4 Cr1 = {0.f,0.f,0.f,0.f}, Cz1 = {0.f,0.f,0.f,0.f}, Cn1 = {0.f,0.f,0.f,0.f};
      #pragma unroll
      for (int kt = 0; kt < 4; ++kt) {
        bf16x8 a = *(const bf16x8*)&hbuf[rb][(16 + c) * HSTR + kt * 32 + klo];
        Cr1 = mfma16(a, wR[0][kt], Cr1);
        Cz1 = mfma16(a, wR[1][kt], Cz1);
        Cn1 = mfma16(a, wR[2][kt], Cn1);
      }
      // ---- group 0: xv + out staging + elementwise + h write ----
      {
        float xv[4];
        if (t > 0) {
          #pragma unroll
          for (int r = 0; r < 4; ++r) {
            float4 xp = *(const float4*)xq[0][4 * grp + r];
            xv[r] = xp.x + xp.y + xp.z + xp.w;   // b2v inside tile-3 partial
          }
          if (c == 0 && w == 0) {
            #pragma unroll
            for (int r = 0; r < 4; ++r)
              outstage[(4 * grp + r) * 52 + (t - 1)] = xv[r];
          }
        } else {
          #pragma unroll
          for (int r = 0; r < 4; ++r)
            xv[r] = enc[(size_t)(seqbase + 4 * grp + r) * 100 + 99];
        }
        #pragma unroll
        for (int r = 0; r < 4; ++r) {
          float ar = fmaf(xv[r], wihr, Cr0[r]);
          float rg = sigm2(ar);
          float az = fmaf(xv[r], wihz, Cz0[r]);
          float zg = sigm2(az);
          float bn = fmaf(rg, Cn0[r], fmaf(xv[r], wihn, bin_));
          float ng = tanh2(bn);
          float hn = fmaf(zg, h_old[0][r] - ng, ng);
          h_old[0][r] = hn;
          if (u < HSTR)
            hbuf[wb][(4 * grp + r) * HSTR + u] = (__bf16)(vu ? hn : padf);
        }
      }
      // ---- group 1: xv + out staging + elementwise + h write ----
      {
        float xv[4];
        if (t > 0) {
          #pragma unroll
          for (int r = 0; r < 4; ++r) {
            float4 xp = *(const float4*)xq[1][4 * grp + r];
            xv[r] = xp.x + xp.y + xp.z + xp.w;
          }
          if (c == 0 && w == 3) {
            #pragma unroll
            for (int r = 0; r < 4; ++r)
              outstage[(16 + 4 * grp + r) * 52 + (t - 1)] = xv[r];
          }
        } else {
          #pragma unroll
          for (int r = 0; r < 4; ++r)
            xv[r] = enc[(size_t)(seqbase + 16 + 4 * grp + r) * 100 + 99];
        }
        #pragma unroll
        for (int r = 0; r < 4; ++r) {
          float ar = fmaf(xv[r], wihr, Cr1[r]);
          float rg = sigm2(ar);
          float az = fmaf(xv[r], wihz, Cz1[r]);
          float zg = sigm2(az);
          float bn = fmaf(rg, Cn1[r], fmaf(xv[r], wihn, bin_));
          float ng = tanh2(bn);
          float hn = fmaf(zg, h_old[1][r] - ng, ng);
          h_old[1][r] = hn;
          if (u < HSTR)
            hbuf[wb][(16 + 4 * grp + r) * HSTR + u] = (__bf16)(vu ? hn : padf);
        }
      }
    } else {
      // t == 50: only the final out staging (y_49); b2v already in tile-3 partial
      #pragma unroll
      for (int g = 0; g < 2; ++g) {
        if (c == 0 && w == 3 * g) {
          #pragma unroll
          for (int r = 0; r < 4; ++r) {
            float4 xp = *(const float4*)xq[g][4 * grp + r];
            outstage[(16 * g + 4 * grp + r) * 52 + (t - 1)] =
                xp.x + xp.y + xp.z + xp.w;
          }
        }
      }
    }
    __syncthreads();  // barrier 2: h ready for next step
  }

  // ---------- coalesced output flush ----------
  for (int i = tid; i < 32 * 50; i += 448) {
    int s = i / 50, tp = i - s * 50;
    out[(size_t)(seqbase + s) * 50 + tp] = outstage[s * 52 + tp];
  }
}

extern "C" void kernel_launch(void* const* d_in, const int* in_sizes, int n_in,
                              void* d_out, int out_size, void* d_ws, size_t ws_size,
                              hipStream_t stream) {
  const float* enc   = (const float*)d_in[0];
  const float* w_enc = (const float*)d_in[1];
  const float* b_enc = (const float*)d_in[2];
  const float* w_ih  = (const float*)d_in[3];
  const float* b_ih  = (const float*)d_in[4];
  const float* w_hh  = (const float*)d_in[5];
  const float* b_hh  = (const float*)d_in[6];
  const float* w1    = (const float*)d_in[7];
  const float* b1    = (const float*)d_in[8];
  const float* w2    = (const float*)d_in[9];
  const float* b2    = (const float*)d_in[10];
  __bf16* ws = (__bf16*)d_ws;
  float* out = (float*)d_out;

  prep_kernel<<<256, 256, 0, stream>>>(w_enc, b_enc, w_hh, b_ih, b_hh, w1, b1, ws);
  gru_main<<<32768 / 32, 448, 0, stream>>>(enc, w_ih, b_ih, w2, b2, ws, out);
}

// Round 13
// 270.106 us; speedup vs baseline: 1.4089x; 1.1574x over previous
//
#include <hip/hip_runtime.h>

template <int N> struct IC { static constexpr int v = N; };

typedef __bf16 bf16x8 __attribute__((ext_vector_type(8)));
typedef float f32x4 __attribute__((ext_vector_type(4)));

// workspace layout (bf16 elements):
//   [0)      Weff   [112][128]  (unit, k)  pre-scaled by 2*log2e, col100 = 2*log2e*b_enc
//                                          pad rows 100..111: col100 = 30 (h0 pad = 1.0 exactly)
//   [14336)  whh_p  [3][112][128]          r,z pre-scaled by log2e (col100 = log2e*(b_ih+b_hh));
//                                          n pre-scaled by 2*log2e (col100 = 2*log2e*b_hh_n)
//                                          z pad rows 100..111: col100 = 30 (zg=1 -> h_pad stable)
//   [57344)  w1_p   [64][128]  (yunit, k)  col100 = b1
#define WS_WENC 0
#define WS_WHH  14336
#define WS_W1   57344
#define LOG2E 1.4426950408889634f
// hbuf row stride 104; buffer 3360 = 32*104 + 32 guard so K=128 MFMA overrun reads
// stay inside (finite bf16; weight K-cols 101..127 are zero -> contributes x*0).
#define HSTR 104
#define HBUFLEN 3360

__device__ __forceinline__ float fast_exp2(float x) {
#if __has_builtin(__builtin_amdgcn_exp2f)
  return __builtin_amdgcn_exp2f(x);
#else
  return exp2f(x);
#endif
}
__device__ __forceinline__ float fast_rcp(float x) {
#if __has_builtin(__builtin_amdgcn_rcpf)
  return __builtin_amdgcn_rcpf(x);
#else
  return 1.f / x;
#endif
}

__global__ void prep_kernel(const float* __restrict__ w_enc,
                            const float* __restrict__ b_enc,
                            const float* __restrict__ w_hh,
                            const float* __restrict__ b_ih,
                            const float* __restrict__ b_hh,
                            const float* __restrict__ w1,
                            const float* __restrict__ b1,
                            __bf16* __restrict__ ws) {
  int idx = blockIdx.x * 256 + threadIdx.x;
  if (idx < 14336) {
    int i = idx >> 7, n = idx & 127;
    float acc = 0.f;
    if (i < 100) {
      if (n < 100) {
        const float* wr = w_enc + i * 202;
        acc = wr[n];
        #pragma unroll 1
        for (int k = 0; k <= 50; ++k) {
          int m = (k * n) % 100;                 // exact range reduction
          float th = 0.062831853071795864f * (float)m;
          float s, c;
          __sincosf(th, &s, &c);
          acc += wr[100 + k] * c - wr[151 + k] * s;
        }
        acc *= 2.f * LOG2E;
      } else if (n == 100) {
        acc = 2.f * LOG2E * b_enc[i];
      }
    } else if (n == 100) {
      acc = 30.f;   // pad rows: tanh2(30) == 1.0 exactly -> h0 pad lanes = 1.0
    }
    ws[idx] = (__bf16)acc;
  } else if (idx < 57344) {
    int j = idx - 14336;
    int g = j / 14336;
    int rem = j - g * 14336;
    int u2 = rem >> 7, c2 = rem & 127;
    float scale = (g == 2) ? 2.f * LOG2E : LOG2E;
    float v = 0.f;
    if (u2 < 100) {
      if (c2 < 100) v = scale * w_hh[(g * 100 + u2) * 100 + c2];
      else if (c2 == 100) {
        v = (g == 2) ? scale * b_hh[200 + u2]
                     : scale * (b_ih[g * 100 + u2] + b_hh[g * 100 + u2]);
      }
    } else if (g == 1 && c2 == 100) {
      v = 30.f;     // z-gate pad bias: zg = 1.0 exactly -> hn = h_old (pad col stable)
    }
    ws[idx] = (__bf16)v;
  } else if (idx < 65536) {
    int j = idx - 57344;
    int r2 = j >> 7, c2 = j & 127;
    float v = 0.f;
    if (r2 < 50) {
      if (c2 < 100) v = w1[r2 * 100 + c2];
      else if (c2 == 100) v = b1[r2];
    }
    ws[idx] = (__bf16)v;
  }
}

__device__ __forceinline__ f32x4 mfma16(bf16x8 a, bf16x8 b, f32x4 c) {
  return __builtin_amdgcn_mfma_f32_16x16x32_bf16(a, b, c, 0, 0, 0);
}
// input already scaled by log2e:  sigm = rcp(1 + 2^-a)
__device__ __forceinline__ float sigm2(float a) { return fast_rcp(1.f + fast_exp2(-a)); }
// input already scaled by 2*log2e: tanh = 2*rcp(1 + 2^-b) - 1
__device__ __forceinline__ float tanh2(float b) { return fmaf(2.f, fast_rcp(1.f + fast_exp2(-b)), -1.f); }

// R12 structure (best: 313us) with the instruction-count diet:
//  - t-loop peeled (t=0 / t=1..48 double-steps / t=49 / t=50) so rb is a COMPILE-TIME
//    constant -> hbuf[rb] is a static LDS base; all ds offsets fold to lane-reg + imm.
//  - pad-lane selects eliminated via weight-side pad biases (see prep: Weff/z col100=30,
//    making pad h EXACTLY stable at 1.0 / 0.0 with zero extra instructions).
//  - w2 in registers; no w2l. launch_bounds(448,2) gives the allocator VGPR headroom
//    (<=292 VGPR/wave still sustains 7 waves/SIMD; LDS 38.0 KB keeps 4 blocks/CU).
// MFMA 16x16x32_bf16; C/D layout: col = lane&15, row = 4*(lane>>4)+reg (HW-verified).
// Bias trick: h column 100 pinned to 1.0; weight column 100 carries the biases.
__global__ __launch_bounds__(448, 2)
void gru_main(const float* __restrict__ enc,
              const float* __restrict__ w_ih,
              const float* __restrict__ b_ih,
              const float* __restrict__ w2,
              const float* __restrict__ b2,
              const __bf16* __restrict__ ws,
              float* __restrict__ out) {
  __shared__ __align__(16) __bf16 hbuf[2][HBUFLEN];   // [buf][seq*HSTR + unit], +guard
  __shared__ __align__(16) __bf16 wYl[64 * 136];      // w1_p restrided 128->136
  __shared__ __align__(16) float xq[2][16][4];        // y tile-partials [group][seq][tile]
  __shared__ __align__(16) float outstage[32 * 52];   // [seq][t], stride 52

  const int tid = threadIdx.x;
  const int w = tid >> 6;
  const int l = tid & 63;
  const int c = l & 15;        // tile column / seq-in-group
  const int grp = l >> 4;      // 0..3
  const int klo = 8 * grp;     // within-K-tile offset
  const int seqbase = blockIdx.x * 32;
  const int u = 16 * w + c;    // this lane's hidden unit
  const bool vu = (u < 100);

  // init LDS h-buffers (incl. guards): zeros (pad col handled by weight-side biases)
  for (int i = tid; i < 2 * HBUFLEN; i += 448)
    hbuf[0][i] = (__bf16)0.f;
  // stage w1_p into LDS with stride restrip 128 -> 136 (1024 16B chunks)
  for (int i = tid; i < 1024; i += 448) {
    int row = i >> 4, off = (i & 15) * 8;
    *(bf16x8*)&wYl[row * 136 + off] = *(const bf16x8*)(ws + WS_W1 + row * 128 + off);
  }

  // per-lane constants (pre-scaled)
  float wihr = 0.f, wihz = 0.f, wihn = 0.f, bin_ = 0.f;
  if (vu) {
    wihr = w_ih[u] * LOG2E;
    wihz = w_ih[100 + u] * LOG2E;
    wihn = w_ih[200 + u] * (2.f * LOG2E);
    bin_ = b_ih[200 + u] * (2.f * LOG2E);
  }
  // y-task assignment
  const int ytile = (w < 3) ? w : ((w == 3) ? 3 : (w - 4));
  const int yg0 = (w < 4) ? 0 : 1;
  const bool dual = (w == 3);
  const float b2v = b2[0];
  float w2v[4];
  #pragma unroll
  for (int r = 0; r < 4; ++r) {
    int yu = ytile * 16 + 4 * grp + r;
    w2v[r] = (yu < 50) ? w2[yu] : 0.f;
  }

  // resident w_hh fragments (shared across both seq groups)
  bf16x8 wR[3][4];
  #pragma unroll
  for (int g = 0; g < 3; ++g) {
    #pragma unroll
    for (int kt = 0; kt < 4; ++kt)
      wR[g][kt] = *(const bf16x8*)(ws + WS_WHH + (g * 112 + u) * 128 + kt * 32 + klo);
  }

  // loop-invariant lane base offsets (elements)
  const int g0base = c * HSTR + klo;                 // gate A-frag reads, group via imm
  const int agbase = (16 * yg0 + c) * HSTR + klo;    // y-phase B-frag (non-dual)
  const int wybase = (ytile * 16 + c) * 136 + klo;   // y-phase A-frag (w1)
  const int wbase  = (4 * grp) * HSTR + u;           // h writes, row r & group via imm

  // ---------- encoder: h0 = tanh(sig @ Weff^T), DFT + bias folded into Weff ----------
  float h_old[2][4];
  {
    #pragma unroll
    for (int g = 0; g < 2; ++g) {
      f32x4 hc = {0.f, 0.f, 0.f, 0.f};
      const float* srow = enc + (size_t)(seqbase + 16 * g + c) * 100;
      #pragma unroll
      for (int kt = 0; kt < 4; ++kt) {
        bf16x8 wE = *(const bf16x8*)(ws + WS_WENC + u * 128 + kt * 32 + klo);
        int t0 = kt * 32 + klo;
        float f0 = 0.f, f1 = 0.f, f2 = 0.f, f3 = 0.f, f4 = 0.f, f5 = 0.f, f6 = 0.f, f7 = 0.f;
        if (t0 + 8 <= 100) {
          float4 va = *(const float4*)(srow + t0);
          float4 vb = *(const float4*)(srow + t0 + 4);
          f0 = va.x; f1 = va.y; f2 = va.z; f3 = va.w;
          f4 = vb.x; f5 = vb.y; f6 = vb.z; f7 = vb.w;
        } else if (t0 < 100) {  // t0 == 96: 4 real + slot 100 = 1.0 (bias)
          float4 va = *(const float4*)(srow + t0);
          f0 = va.x; f1 = va.y; f2 = va.z; f3 = va.w;
          f4 = 1.f;
        }
        bf16x8 a;
        a[0] = (__bf16)f0; a[1] = (__bf16)f1; a[2] = (__bf16)f2; a[3] = (__bf16)f3;
        a[4] = (__bf16)f4; a[5] = (__bf16)f5; a[6] = (__bf16)f6; a[7] = (__bf16)f7;
        hc = mfma16(a, wE, hc);
      }
      #pragma unroll
      for (int r = 0; r < 4; ++r) h_old[g][r] = tanh2(hc[r]);  // pad lanes self-consistent
    }
  }

  __syncthreads();  // LDS init + wYl staging complete
  if (u < HSTR) {
    #pragma unroll
    for (int g = 0; g < 2; ++g)
      #pragma unroll
      for (int r = 0; r < 4; ++r)
        hbuf[0][wbase + (16 * g + r) * HSTR] = (__bf16)h_old[g][r];
  }
  __syncthreads();

  // ---------- step-phase lambdas (rb/g compile-time via IC<>) ----------
  auto yPhase = [&](auto rbc) {
    constexpr int RB = decltype(rbc)::v;
    if (!dual) {
      f32x4 Cy = {0.f, 0.f, 0.f, 0.f};
      #pragma unroll
      for (int kt = 0; kt < 4; ++kt) {
        bf16x8 wyf = *(const bf16x8*)&wYl[wybase + kt * 32];
        bf16x8 ag  = *(const bf16x8*)&hbuf[RB][agbase + kt * 32];
        Cy = mfma16(wyf, ag, Cy);
      }
      float p = 0.f;
      #pragma unroll
      for (int r = 0; r < 4; ++r) {
        float v = Cy[r];
        v = fmaxf(v, 0.01f * v);     // leaky_relu (b1 folded via bias column)
        p = fmaf(w2v[r], v, p);
      }
      p += __shfl_xor(p, 16);
      p += __shfl_xor(p, 32);
      if (l < 16) xq[yg0][l][ytile] = p;
    } else {
      // wave 3: tile 3 for both groups; b2v folded into this partial
      #pragma unroll
      for (int g = 0; g < 2; ++g) {
        f32x4 Cy = {0.f, 0.f, 0.f, 0.f};
        #pragma unroll
        for (int kt = 0; kt < 4; ++kt) {
          bf16x8 wyf = *(const bf16x8*)&wYl[wybase + kt * 32];
          bf16x8 ag  = *(const bf16x8*)&hbuf[RB][g0base + g * 16 * HSTR + kt * 32];
          Cy = mfma16(wyf, ag, Cy);
        }
        float p = 0.f;
        #pragma unroll
        for (int r = 0; r < 4; ++r) {
          float v = Cy[r];
          v = fmaxf(v, 0.01f * v);
          p = fmaf(w2v[r], v, p);
        }
        p += __shfl_xor(p, 16);
        p += __shfl_xor(p, 32);
        if (l < 16) xq[g][l][3] = p + b2v;
      }
    }
  };

  auto gates = [&](auto rbc, auto gc, f32x4& Cr, f32x4& Cz, f32x4& Cn) {
    constexpr int RB = decltype(rbc)::v;
    constexpr int G  = decltype(gc)::v;
    Cr = f32x4{0.f, 0.f, 0.f, 0.f};
    Cz = f32x4{0.f, 0.f, 0.f, 0.f};
    Cn = f32x4{0.f, 0.f, 0.f, 0.f};
    #pragma unroll
    for (int kt = 0; kt < 4; ++kt) {
      bf16x8 a = *(const bf16x8*)&hbuf[RB][g0base + G * 16 * HSTR + kt * 32];
      Cr = mfma16(a, wR[0][kt], Cr);
      Cz = mfma16(a, wR[1][kt], Cz);
      Cn = mfma16(a, wR[2][kt], Cn);
    }
  };

  auto elem = [&](int t, auto wbc, auto gc, auto firstc,
                  f32x4& Cr, f32x4& Cz, f32x4& Cn) {
    constexpr int WB = decltype(wbc)::v;
    constexpr int G  = decltype(gc)::v;
    constexpr int F  = decltype(firstc)::v;
    float xv[4];
    if constexpr (F) {
      #pragma unroll
      for (int r = 0; r < 4; ++r)
        xv[r] = enc[(size_t)(seqbase + 16 * G + 4 * grp + r) * 100 + 99];
    } else {
      #pragma unroll
      for (int r = 0; r < 4; ++r) {
        float4 xp = *(const float4*)xq[G][4 * grp + r];
        xv[r] = xp.x + xp.y + xp.z + xp.w;   // b2v inside tile-3 partial
      }
      if (c == 0 && w == 3 * G) {
        #pragma unroll
        for (int r = 0; r < 4; ++r)
          outstage[(16 * G + 4 * grp + r) * 52 + (t - 1)] = xv[r];
      }
    }
    #pragma unroll
    for (int r = 0; r < 4; ++r) {
      float ar = fmaf(xv[r], wihr, Cr[r]);
      float rg = sigm2(ar);
      float az = fmaf(xv[r], wihz, Cz[r]);
      float zg = sigm2(az);
      float bn = fmaf(rg, Cn[r], fmaf(xv[r], wihn, bin_));
      float ng = tanh2(bn);
      h_old[G][r] = fmaf(zg, h_old[G][r] - ng, ng);
    }
    if (u < HSTR) {
      #pragma unroll
      for (int r = 0; r < 4; ++r)
        hbuf[WB][wbase + (16 * G + r) * HSTR] = (__bf16)h_old[G][r];
    }
  };

  auto fullStep = [&](int t, auto rbc, auto firstc) {
    constexpr int RB = decltype(rbc)::v;
    constexpr int F  = decltype(firstc)::v;
    if constexpr (!F) yPhase(rbc);
    f32x4 Cr0, Cz0, Cn0;
    gates(rbc, IC<0>{}, Cr0, Cz0, Cn0);
    if constexpr (!F) __syncthreads();   // barrier 1: xq ready
    f32x4 Cr1, Cz1, Cn1;
    gates(rbc, IC<1>{}, Cr1, Cz1, Cn1);  // issued first post-B1, hides under g0 elem
    elem(t, IC<RB ^ 1>{}, IC<0>{}, firstc, Cr0, Cz0, Cn0);
    elem(t, IC<RB ^ 1>{}, IC<1>{}, firstc, Cr1, Cz1, Cn1);
    __syncthreads();                     // barrier 2: h ready for next step
  };

  // ---------- decoder ----------
  fullStep(0, IC<0>{}, IC<1>{});                 // t = 0 (xv from enc, no y-phase)
  #pragma unroll 1
  for (int tt = 1; tt < 49; tt += 2) {           // t = 1..48, rb compile-time per copy
    fullStep(tt,     IC<1>{}, IC<0>{});
    fullStep(tt + 1, IC<0>{}, IC<0>{});
  }
  fullStep(49, IC<1>{}, IC<0>{});                // t = 49
  // t = 50: y_49 only
  yPhase(IC<0>{});
  __syncthreads();
  if (c == 0 && (w == 0 || w == 3)) {
    const int G = (w == 3);
    #pragma unroll
    for (int r = 0; r < 4; ++r) {
      float4 xp = *(const float4*)xq[G][4 * grp + r];
      outstage[(16 * G + 4 * grp + r) * 52 + 49] = xp.x + xp.y + xp.z + xp.w;
    }
  }
  __syncthreads();

  // ---------- coalesced output flush ----------
  for (int i = tid; i < 32 * 50; i += 448) {
    int s = i / 50, tp = i - s * 50;
    out[(size_t)(seqbase + s) * 50 + tp] = outstage[s * 52 + tp];
  }
}

extern "C" void kernel_launch(void* const* d_in, const int* in_sizes, int n_in,
                              void* d_out, int out_size, void* d_ws, size_t ws_size,
                              hipStream_t stream) {
  const float* enc   = (const float*)d_in[0];
  const float* w_enc = (const float*)d_in[1];
  const float* b_enc = (const float*)d_in[2];
  const float* w_ih  = (const float*)d_in[3];
  const float* b_ih  = (const float*)d_in[4];
  const float* w_hh  = (const float*)d_in[5];
  const float* b_hh  = (const float*)d_in[6];
  const float* w1    = (const float*)d_in[7];
  const float* b1    = (const float*)d_in[8];
  const float* w2    = (const float*)d_in[9];
  const float* b2    = (const float*)d_in[10];
  __bf16* ws = (__bf16*)d_ws;
  float* out = (float*)d_out;

  prep_kernel<<<256, 256, 0, stream>>>(w_enc, b_enc, w_hh, b_ih, b_hh, w1, b1, ws);
  gru_main<<<32768 / 32, 448, 0, stream>>>(enc, w_ih, b_ih, w2, b2, ws, out);
}